// Round 2
// baseline (421.025 us; speedup 1.0000x reference)
//
#include <hip/hip_runtime.h>
#include <hip/hip_bf16.h>
#include <math.h>

#define DD 768
#define BB 32
#define PP 512
#define TT 512
#define CC 97
#define THRESH 0.8f

typedef __attribute__((ext_vector_type(8))) short short8;
typedef __attribute__((ext_vector_type(4))) float f32x4;

// ---------------- stage 1a: normalize entity pairs -> bf16 unit vecs ----------
__global__ void norm_pairs_kernel(const float* __restrict__ pairs,
                                  __hip_bfloat16* __restrict__ ph,
                                  __hip_bfloat16* __restrict__ pt) {
    int row = blockIdx.x;            // B*P rows
    int tid = threadIdx.x;           // 256 threads
    const float* src = pairs + (size_t)row * (2 * DD);

    float xh[3], xt[3];
    float sh = 0.f, st = 0.f;
#pragma unroll
    for (int j = 0; j < 3; ++j) {
        xh[j] = src[j * 256 + tid];
        xt[j] = src[DD + j * 256 + tid];
        sh += xh[j] * xh[j];
        st += xt[j] * xt[j];
    }
    // wave reduce (width 64)
    for (int off = 32; off; off >>= 1) {
        sh += __shfl_down(sh, off);
        st += __shfl_down(st, off);
    }
    __shared__ float red[2][5];
    int wid = tid >> 6, lane = tid & 63;
    if (lane == 0) { red[0][wid] = sh; red[1][wid] = st; }
    __syncthreads();
    if (tid == 0) {
        float a = red[0][0] + red[0][1] + red[0][2] + red[0][3];
        float b = red[1][0] + red[1][1] + red[1][2] + red[1][3];
        red[0][4] = 1.0f / fmaxf(sqrtf(a), 1e-8f);
        red[1][4] = 1.0f / fmaxf(sqrtf(b), 1e-8f);
    }
    __syncthreads();
    float ih = red[0][4], it = red[1][4];
    __hip_bfloat16* dh = ph + (size_t)row * DD;
    __hip_bfloat16* dt = pt + (size_t)row * DD;
#pragma unroll
    for (int j = 0; j < 3; ++j) {
        dh[j * 256 + tid] = __float2bfloat16(xh[j] * ih);
        dt[j * 256 + tid] = __float2bfloat16(xt[j] * it);
    }
}

// ---------------- stage 1b: normalize triplets -> bf16 unit vecs + rel ids ----
__global__ void norm_trip_kernel(const float* __restrict__ trip,
                                 __hip_bfloat16* __restrict__ gh,
                                 __hip_bfloat16* __restrict__ gt,
                                 int* __restrict__ rel) {
    int row = blockIdx.x;            // B*T rows
    int tid = threadIdx.x;
    const float* src = trip + (size_t)row * (2 * DD + 1);

    float xh[3], xt[3];
    float sh = 0.f, st = 0.f;
#pragma unroll
    for (int j = 0; j < 3; ++j) {
        xh[j] = src[j * 256 + tid];
        xt[j] = src[DD + 1 + j * 256 + tid];
        sh += xh[j] * xh[j];
        st += xt[j] * xt[j];
    }
    for (int off = 32; off; off >>= 1) {
        sh += __shfl_down(sh, off);
        st += __shfl_down(st, off);
    }
    __shared__ float red[2][5];
    int wid = tid >> 6, lane = tid & 63;
    if (lane == 0) { red[0][wid] = sh; red[1][wid] = st; }
    __syncthreads();
    if (tid == 0) {
        float a = red[0][0] + red[0][1] + red[0][2] + red[0][3];
        float b = red[1][0] + red[1][1] + red[1][2] + red[1][3];
        red[0][4] = 1.0f / fmaxf(sqrtf(a), 1e-8f);
        red[1][4] = 1.0f / fmaxf(sqrtf(b), 1e-8f);
        rel[row] = (int)src[DD];
    }
    __syncthreads();
    float ih = red[0][4], it = red[1][4];
    __hip_bfloat16* dh = gh + (size_t)row * DD;
    __hip_bfloat16* dt = gt + (size_t)row * DD;
#pragma unroll
    for (int j = 0; j < 3; ++j) {
        dh[j * 256 + tid] = __float2bfloat16(xh[j] * ih);
        dt[j * 256 + tid] = __float2bfloat16(xt[j] * it);
    }
}

// ---------------- stage 2: all-pairs sims via MFMA + thresholded argmax -------
// grid: (P/16, B).  block: 256 = 4 waves.  Wave w covers t-range [w*128,(w+1)*128).
// Register double-buffered k-loop: next k-step's 10 loads fly during this
// step's 8 MFMAs (R1 fix for the fully-serialized-load bottleneck).
__global__ __launch_bounds__(256) void match_kernel(
        const __hip_bfloat16* __restrict__ ph, const __hip_bfloat16* __restrict__ pt,
        const __hip_bfloat16* __restrict__ gh, const __hip_bfloat16* __restrict__ gt,
        const int* __restrict__ rel, int* __restrict__ tgt) {
    int b = blockIdx.y;
    int ptile = blockIdx.x;                  // 16 pred rows per block
    int tid = threadIdx.x;
    int w = tid >> 6, l = tid & 63;
    int l15 = l & 15, lg = l >> 4;           // 16-lane group id 0..3

    // per-lane base pointers (element offsets; rows are 16B aligned)
    const __hip_bfloat16* pA_h = ph + ((size_t)(b * PP + ptile * 16) + l15) * DD + lg * 8;
    const __hip_bfloat16* pA_t = pt + ((size_t)(b * PP + ptile * 16) + l15) * DD + lg * 8;
    const __hip_bfloat16* gB_h = gh + ((size_t)b * TT + l15) * DD + lg * 8;
    const __hip_bfloat16* gB_t = gt + ((size_t)b * TT + l15) * DD + lg * 8;

    float bestv[4];
    int bestt[4];
#pragma unroll
    for (int r = 0; r < 4; ++r) { bestv[r] = -INFINITY; bestt[r] = 0; }

    for (int q = 0; q < 2; ++q) {
        int t0 = (w * 2 + q) * 64;
        const __hip_bfloat16* bh_base = gB_h + (size_t)t0 * DD;
        const __hip_bfloat16* bt_base = gB_t + (size_t)t0 * DD;

        f32x4 accH[4], accT[4];
#pragma unroll
        for (int n = 0; n < 4; ++n) {
            accH[n] = (f32x4){0.f, 0.f, 0.f, 0.f};
            accT[n] = (f32x4){0.f, 0.f, 0.f, 0.f};
        }

        short8 A_ah, A_at, A_bh0, A_bh1, A_bh2, A_bh3, A_bt0, A_bt1, A_bt2, A_bt3;
        short8 B_ah, B_at, B_bh0, B_bh1, B_bh2, B_bh3, B_bt0, B_bt1, B_bt2, B_bt3;

#define LOADSET(S, koff)                                                        \
        do {                                                                    \
            S##_ah  = *(const short8*)(pA_h + (koff));                          \
            S##_at  = *(const short8*)(pA_t + (koff));                          \
            S##_bh0 = *(const short8*)(bh_base + (size_t)( 0) * DD + (koff));   \
            S##_bh1 = *(const short8*)(bh_base + (size_t)(16) * DD + (koff));   \
            S##_bh2 = *(const short8*)(bh_base + (size_t)(32) * DD + (koff));   \
            S##_bh3 = *(const short8*)(bh_base + (size_t)(48) * DD + (koff));   \
            S##_bt0 = *(const short8*)(bt_base + (size_t)( 0) * DD + (koff));   \
            S##_bt1 = *(const short8*)(bt_base + (size_t)(16) * DD + (koff));   \
            S##_bt2 = *(const short8*)(bt_base + (size_t)(32) * DD + (koff));   \
            S##_bt3 = *(const short8*)(bt_base + (size_t)(48) * DD + (koff));   \
        } while (0)

#define MFMASET(S)                                                                      \
        do {                                                                            \
            accH[0] = __builtin_amdgcn_mfma_f32_16x16x32_bf16(S##_ah, S##_bh0, accH[0], 0, 0, 0); \
            accH[1] = __builtin_amdgcn_mfma_f32_16x16x32_bf16(S##_ah, S##_bh1, accH[1], 0, 0, 0); \
            accH[2] = __builtin_amdgcn_mfma_f32_16x16x32_bf16(S##_ah, S##_bh2, accH[2], 0, 0, 0); \
            accH[3] = __builtin_amdgcn_mfma_f32_16x16x32_bf16(S##_ah, S##_bh3, accH[3], 0, 0, 0); \
            accT[0] = __builtin_amdgcn_mfma_f32_16x16x32_bf16(S##_at, S##_bt0, accT[0], 0, 0, 0); \
            accT[1] = __builtin_amdgcn_mfma_f32_16x16x32_bf16(S##_at, S##_bt1, accT[1], 0, 0, 0); \
            accT[2] = __builtin_amdgcn_mfma_f32_16x16x32_bf16(S##_at, S##_bt2, accT[2], 0, 0, 0); \
            accT[3] = __builtin_amdgcn_mfma_f32_16x16x32_bf16(S##_at, S##_bt3, accT[3], 0, 0, 0); \
        } while (0)

        LOADSET(A, 0);
#pragma unroll
        for (int s = 0; s < 24; s += 2) {
            if (s + 1 < 24) LOADSET(B, (s + 1) * 32);
            MFMASET(A);
            if (s + 2 < 24) LOADSET(A, (s + 2) * 32);
            if (s + 1 < 24) MFMASET(B);
        }
#undef LOADSET
#undef MFMASET

        // threshold + scored + running argmax (t increases with q,n -> strict > keeps first)
#pragma unroll
        for (int n = 0; n < 4; ++n) {
#pragma unroll
            for (int r = 0; r < 4; ++r) {
                float h = accH[n][r], tl = accT[n][r];
                bool ok = (h > THRESH) && (tl > THRESH);
                float sc = ok ? 0.5f * (h + tl) : -INFINITY;
                int t = t0 + n * 16 + l15;
                if (sc > bestv[r]) { bestv[r] = sc; bestt[r] = t; }
            }
        }
    }

    // cross-lane reduce within each 16-lane group (cols of the C tile)
#pragma unroll
    for (int r = 0; r < 4; ++r) {
        float v = bestv[r]; int t = bestt[r];
        for (int m = 1; m < 16; m <<= 1) {
            float v2 = __shfl_xor(v, m);
            int t2 = __shfl_xor(t, m);
            if (v2 > v || (v2 == v && t2 < t)) { v = v2; t = t2; }
        }
        bestv[r] = v; bestt[r] = t;
    }

    // merge the 4 waves (disjoint t-ranges) via LDS
    __shared__ float sv[4][16];
    __shared__ int stt[4][16];
    if (l15 == 0) {
#pragma unroll
        for (int r = 0; r < 4; ++r) {
            sv[w][lg * 4 + r] = bestv[r];
            stt[w][lg * 4 + r] = bestt[r];
        }
    }
    __syncthreads();
    if (tid < 16) {
        float v = sv[0][tid]; int t = stt[0][tid];
#pragma unroll
        for (int ww = 1; ww < 4; ++ww) {
            float v2 = sv[ww][tid]; int t2 = stt[ww][tid];
            if (v2 > v || (v2 == v && t2 < t)) { v = v2; t = t2; }
        }
        int target = (v > -INFINITY) ? rel[b * TT + t] : 0;
        tgt[b * PP + ptile * 16 + tid] = target;
    }
}

// ---------------- stage 3: per-row NLL from log-softmax ----------------------
// block = 256 = 4 waves, one row per wave. partials[block] = sum of 4 nll values.
__global__ void nll_kernel(const float* __restrict__ preds,
                           const int* __restrict__ tgt,
                           float* __restrict__ partials) {
    int w = threadIdx.x >> 6, l = threadIdx.x & 63;
    int row = blockIdx.x * 4 + w;
    const float* x = preds + (size_t)row * CC;

    float a = x[l];
    float b2 = (l + 64 < CC) ? x[l + 64] : -INFINITY;
    float mx = fmaxf(a, b2);
    for (int m = 32; m; m >>= 1) mx = fmaxf(mx, __shfl_xor(mx, m));
    float e = __expf(a - mx) + ((l + 64 < CC) ? __expf(b2 - mx) : 0.0f);
    for (int m = 32; m; m >>= 1) e += __shfl_xor(e, m);

    __shared__ float part[4];
    if (l == 0) {
        int tg = tgt[row];
        part[w] = mx + logf(e) - x[tg];
    }
    __syncthreads();
    if (threadIdx.x == 0)
        partials[blockIdx.x] = part[0] + part[1] + part[2] + part[3];
}

// ---------------- stage 4: final mean ----------------------------------------
__global__ void final_reduce_kernel(const float* __restrict__ partials, int n,
                                    float* __restrict__ out) {
    float s = 0.f;
    for (int i = threadIdx.x; i < n; i += 256) s += partials[i];
    for (int m = 32; m; m >>= 1) s += __shfl_xor(s, m);
    __shared__ float ps[4];
    if ((threadIdx.x & 63) == 0) ps[threadIdx.x >> 6] = s;
    __syncthreads();
    if (threadIdx.x == 0)
        out[0] = (ps[0] + ps[1] + ps[2] + ps[3]) / (float)(BB * PP);
}

extern "C" void kernel_launch(void* const* d_in, const int* in_sizes, int n_in,
                              void* d_out, int out_size, void* d_ws, size_t ws_size,
                              hipStream_t stream) {
    const float* pairs = (const float*)d_in[0];  // [B,P,1536]
    const float* preds = (const float*)d_in[1];  // [B,P,97]
    const float* trip  = (const float*)d_in[2];  // [B,T,1537]
    float* out = (float*)d_out;

    char* ws = (char*)d_ws;
    size_t vec_bytes = (size_t)BB * PP * DD * sizeof(__hip_bfloat16);  // 25,165,824
    __hip_bfloat16* ph = (__hip_bfloat16*)(ws);
    __hip_bfloat16* pt = (__hip_bfloat16*)(ws + vec_bytes);
    __hip_bfloat16* gh = (__hip_bfloat16*)(ws + 2 * vec_bytes);
    __hip_bfloat16* gt = (__hip_bfloat16*)(ws + 3 * vec_bytes);
    int* rel  = (int*)(ws + 4 * vec_bytes);
    int* tgt  = (int*)(ws + 4 * vec_bytes + (size_t)BB * TT * sizeof(int));
    float* partials = (float*)(ws + 4 * vec_bytes + (size_t)BB * TT * sizeof(int)
                               + (size_t)BB * PP * sizeof(int));

    norm_pairs_kernel<<<BB * PP, 256, 0, stream>>>(pairs, ph, pt);
    norm_trip_kernel<<<BB * TT, 256, 0, stream>>>(trip, gh, gt, rel);
    match_kernel<<<dim3(PP / 16, BB), 256, 0, stream>>>(ph, pt, gh, gt, rel, tgt);
    nll_kernel<<<BB * PP / 4, 256, 0, stream>>>(preds, tgt, partials);
    final_reduce_kernel<<<1, 256, 0, stream>>>(partials, BB * PP / 4, out);
}

// Round 3
// 271.928 us; speedup vs baseline: 1.5483x; 1.5483x over previous
//
#include <hip/hip_runtime.h>
#include <hip/hip_bf16.h>
#include <math.h>

#define DD 768
#define BB 32
#define PP 512
#define TT 512
#define CC 97
#define THRESH 0.8f

typedef __attribute__((ext_vector_type(8))) short short8;
typedef __attribute__((ext_vector_type(4))) float f32x4;

__device__ __forceinline__ void gload16(const void* g, void* l) {
    __builtin_amdgcn_global_load_lds(
        (const __attribute__((address_space(1))) unsigned int*)g,
        (__attribute__((address_space(3))) unsigned int*)l, 16, 0, 0);
}

// ---------------- stage 1a: normalize entity pairs -> bf16 unit vecs ----------
__global__ void norm_pairs_kernel(const float* __restrict__ pairs,
                                  __hip_bfloat16* __restrict__ ph,
                                  __hip_bfloat16* __restrict__ pt) {
    int row = blockIdx.x;            // B*P rows
    int tid = threadIdx.x;           // 256 threads
    const float* src = pairs + (size_t)row * (2 * DD);

    float xh[3], xt[3];
    float sh = 0.f, st = 0.f;
#pragma unroll
    for (int j = 0; j < 3; ++j) {
        xh[j] = src[j * 256 + tid];
        xt[j] = src[DD + j * 256 + tid];
        sh += xh[j] * xh[j];
        st += xt[j] * xt[j];
    }
    for (int off = 32; off; off >>= 1) {
        sh += __shfl_down(sh, off);
        st += __shfl_down(st, off);
    }
    __shared__ float red[2][5];
    int wid = tid >> 6, lane = tid & 63;
    if (lane == 0) { red[0][wid] = sh; red[1][wid] = st; }
    __syncthreads();
    if (tid == 0) {
        float a = red[0][0] + red[0][1] + red[0][2] + red[0][3];
        float b = red[1][0] + red[1][1] + red[1][2] + red[1][3];
        red[0][4] = 1.0f / fmaxf(sqrtf(a), 1e-8f);
        red[1][4] = 1.0f / fmaxf(sqrtf(b), 1e-8f);
    }
    __syncthreads();
    float ih = red[0][4], it = red[1][4];
    __hip_bfloat16* dh = ph + (size_t)row * DD;
    __hip_bfloat16* dt = pt + (size_t)row * DD;
#pragma unroll
    for (int j = 0; j < 3; ++j) {
        dh[j * 256 + tid] = __float2bfloat16(xh[j] * ih);
        dt[j * 256 + tid] = __float2bfloat16(xt[j] * it);
    }
}

// ---------------- stage 1b: normalize triplets -> bf16 unit vecs + rel ids ----
__global__ void norm_trip_kernel(const float* __restrict__ trip,
                                 __hip_bfloat16* __restrict__ gh,
                                 __hip_bfloat16* __restrict__ gt,
                                 int* __restrict__ rel) {
    int row = blockIdx.x;            // B*T rows
    int tid = threadIdx.x;
    const float* src = trip + (size_t)row * (2 * DD + 1);

    float xh[3], xt[3];
    float sh = 0.f, st = 0.f;
#pragma unroll
    for (int j = 0; j < 3; ++j) {
        xh[j] = src[j * 256 + tid];
        xt[j] = src[DD + 1 + j * 256 + tid];
        sh += xh[j] * xh[j];
        st += xt[j] * xt[j];
    }
    for (int off = 32; off; off >>= 1) {
        sh += __shfl_down(sh, off);
        st += __shfl_down(st, off);
    }
    __shared__ float red[2][5];
    int wid = tid >> 6, lane = tid & 63;
    if (lane == 0) { red[0][wid] = sh; red[1][wid] = st; }
    __syncthreads();
    if (tid == 0) {
        float a = red[0][0] + red[0][1] + red[0][2] + red[0][3];
        float b = red[1][0] + red[1][1] + red[1][2] + red[1][3];
        red[0][4] = 1.0f / fmaxf(sqrtf(a), 1e-8f);
        red[1][4] = 1.0f / fmaxf(sqrtf(b), 1e-8f);
        rel[row] = (int)src[DD];
    }
    __syncthreads();
    float ih = red[0][4], it = red[1][4];
    __hip_bfloat16* dh = gh + (size_t)row * DD;
    __hip_bfloat16* dt = gt + (size_t)row * DD;
#pragma unroll
    for (int j = 0; j < 3; ++j) {
        dh[j * 256 + tid] = __float2bfloat16(xh[j] * ih);
        dt[j * 256 + tid] = __float2bfloat16(xt[j] * it);
    }
}

// ---------------- stage 2: LDS-staged fused dual-GEMM + thresholded argmax ----
// Block: 512 thr = 8 waves, 128p x 128t tile of one batch.
// Waves 0-3: head sims (quadrants), waves 4-7: tail sims (same quadrants).
// BK=64, double-buffered LDS (2 x 64KB), global_load_lds w/ pre-swizzled src.
// Per-p best over this block's 128 t -> cand arrays; merge kernel folds 4 tblks.
__global__ __launch_bounds__(512, 2) void match_kernel(
        const __hip_bfloat16* __restrict__ ph, const __hip_bfloat16* __restrict__ pt,
        const __hip_bfloat16* __restrict__ gh, const __hip_bfloat16* __restrict__ gt,
        float* __restrict__ cand_v, int* __restrict__ cand_t) {
    extern __shared__ __align__(16) char lds_raw[];   // 131072 B: 2 x 64KB buffers
    __shared__ float xch[4][64][16];                  // H<->T acc exchange (16 KB)
    __shared__ float bwv[128][2];
    __shared__ int   bwt[128][2];

    // XCD swizzle: group each batch's 16 blocks on one XCD (nwg=512, 512%8==0)
    int swz = (blockIdx.x % 8) * 64 + blockIdx.x / 8;
    int b    = swz >> 4;
    int sub  = swz & 15;
    int pblk = sub >> 2;
    int tblk = sub & 3;

    int tid = threadIdx.x;
    int w = tid >> 6, l = tid & 63;
    int l15 = l & 15, lg = l >> 4;

    const __hip_bfloat16* Ah_g = ph + ((size_t)b * PP + pblk * 128) * DD;
    const __hip_bfloat16* At_g = pt + ((size_t)b * PP + pblk * 128) * DD;
    const __hip_bfloat16* Bh_g = gh + ((size_t)b * TT + tblk * 128) * DD;
    const __hip_bfloat16* Bt_g = gt + ((size_t)b * TT + tblk * 128) * DD;

    // staging source (pre-swizzled so linear LDS dest holds slot^row&7 layout)
    int srow = tid >> 3;                       // 0..63
    int xs   = (tid & 7) ^ (srow & 7);         // swizzled 16B slot within row
    size_t off0 = (size_t)srow * DD + xs * 8;  // elements; round1 = +64 rows

#define STAGE(c, step)                                                          \
    do {                                                                        \
        size_t o0 = off0 + (size_t)(step) * 64;                                 \
        size_t o1 = o0 + (size_t)64 * DD;                                       \
        char* lb = lds_raw + (c) * 65536 + (size_t)tid * 16;                    \
        gload16(Ah_g + o0, lb + 0);                                             \
        gload16(Ah_g + o1, lb + 8192);                                          \
        gload16(At_g + o0, lb + 16384);                                         \
        gload16(At_g + o1, lb + 24576);                                         \
        gload16(Bh_g + o0, lb + 32768);                                         \
        gload16(Bh_g + o1, lb + 40960);                                         \
        gload16(Bt_g + o0, lb + 49152);                                         \
        gload16(Bt_g + o1, lb + 57344);                                         \
    } while (0)

    // per-wave fragment addressing
    int isT = w >> 2;
    int qi = w & 3, qr = qi >> 1, qc = qi & 1;
    int aoff = isT ? 16384 : 0;
    int boff = isT ? 49152 : 32768;
    int xr = l15 & 7;
    int cb0 = (lg ^ xr) * 16;                  // k-slice 0 col byte (s1 = cb0^64)
    int rA[4], rB[4];
#pragma unroll
    for (int i = 0; i < 4; ++i) rA[i] = aoff + (qr * 64 + i * 16 + l15) * 128;
#pragma unroll
    for (int j = 0; j < 4; ++j) rB[j] = boff + (qc * 64 + j * 16 + l15) * 128;

    f32x4 acc[4][4];
#pragma unroll
    for (int i = 0; i < 4; ++i)
#pragma unroll
        for (int j = 0; j < 4; ++j) acc[i][j] = (f32x4){0.f, 0.f, 0.f, 0.f};

    int cur = 0;
    STAGE(0, 0);
    asm volatile("s_waitcnt vmcnt(0)" ::: "memory");
    __syncthreads();

    for (int step = 0; step < 12; ++step) {
        if (step < 11) STAGE(cur ^ 1, step + 1);
        const char* bp = lds_raw + cur * 65536;
        short8 af[4], bf[4];
        // k-slice 0
#pragma unroll
        for (int i = 0; i < 4; ++i) af[i] = *(const short8*)(bp + rA[i] + cb0);
#pragma unroll
        for (int j = 0; j < 4; ++j) bf[j] = *(const short8*)(bp + rB[j] + cb0);
#pragma unroll
        for (int i = 0; i < 4; ++i)
#pragma unroll
            for (int j = 0; j < 4; ++j)
                acc[i][j] = __builtin_amdgcn_mfma_f32_16x16x32_bf16(af[i], bf[j], acc[i][j], 0, 0, 0);
        // k-slice 1
#pragma unroll
        for (int i = 0; i < 4; ++i) af[i] = *(const short8*)(bp + rA[i] + (cb0 ^ 64));
#pragma unroll
        for (int j = 0; j < 4; ++j) bf[j] = *(const short8*)(bp + rB[j] + (cb0 ^ 64));
#pragma unroll
        for (int i = 0; i < 4; ++i)
#pragma unroll
            for (int j = 0; j < 4; ++j)
                acc[i][j] = __builtin_amdgcn_mfma_f32_16x16x32_bf16(af[i], bf[j], acc[i][j], 0, 0, 0);

        asm volatile("s_waitcnt vmcnt(0)" ::: "memory");
        __syncthreads();
        cur ^= 1;
    }
#undef STAGE

    // epilogue: combine H (waves 0-3) with T (waves 4-7), lane-aligned exchange
    int wp = w & 3;
    for (int i = 0; i < 4; ++i) {
        if (w >= 4) {
#pragma unroll
            for (int j = 0; j < 4; ++j)
#pragma unroll
                for (int r = 0; r < 4; ++r)
                    xch[wp][l][j * 4 + r] = acc[i][j][r];
        }
        __syncthreads();
        if (w < 4) {
#pragma unroll
            for (int r = 0; r < 4; ++r) {
                float bv = -INFINITY; int bt = 0x7fffffff;
#pragma unroll
                for (int j = 0; j < 4; ++j) {
                    float h = acc[i][j][r];
                    float t = xch[wp][l][j * 4 + r];
                    bool ok = (h > THRESH) && (t > THRESH);
                    float sc = ok ? 0.5f * (h + t) : -INFINITY;
                    int ti = tblk * 128 + qc * 64 + j * 16 + l15;
                    if (sc > bv || (sc == bv && ti < bt)) { bv = sc; bt = ti; }
                }
                // reduce across the 16 t-lanes (xor masks stay within group)
#pragma unroll
                for (int m = 1; m < 16; m <<= 1) {
                    float v2 = __shfl_xor(bv, m);
                    int t2 = __shfl_xor(bt, m);
                    if (v2 > bv || (v2 == bv && t2 < bt)) { bv = v2; bt = t2; }
                }
                if (l15 == 0) {
                    int p = qr * 64 + i * 16 + lg * 4 + r;
                    bwv[p][qc] = bv;
                    bwt[p][qc] = bt;
                }
            }
        }
        __syncthreads();
    }

    if (tid < 128) {
        float v = bwv[tid][0]; int t = bwt[tid][0];
        float v2 = bwv[tid][1]; int t2 = bwt[tid][1];
        if (v2 > v || (v2 == v && t2 < t)) { v = v2; t = t2; }
        int grow = b * PP + pblk * 128 + tid;
        cand_v[(size_t)grow * 4 + tblk] = v;
        cand_t[(size_t)grow * 4 + tblk] = t;
    }
}

// ---------------- stage 2b: merge 4 t-blocks -> target class -----------------
__global__ void merge_kernel(const float* __restrict__ cand_v,
                             const int* __restrict__ cand_t,
                             const int* __restrict__ rel,
                             int* __restrict__ tgt) {
    int row = blockIdx.x * 256 + threadIdx.x;    // B*P rows
    float v = -INFINITY; int t = 0x7fffffff;
#pragma unroll
    for (int k = 0; k < 4; ++k) {
        float v2 = cand_v[(size_t)row * 4 + k];
        int t2 = cand_t[(size_t)row * 4 + k];
        if (v2 > v || (v2 == v && t2 < t)) { v = v2; t = t2; }
    }
    int b = row >> 9;
    tgt[row] = (v > -INFINITY) ? rel[b * TT + t] : 0;
}

// ---------------- stage 3: per-row NLL from log-softmax ----------------------
__global__ void nll_kernel(const float* __restrict__ preds,
                           const int* __restrict__ tgt,
                           float* __restrict__ partials) {
    int w = threadIdx.x >> 6, l = threadIdx.x & 63;
    int row = blockIdx.x * 4 + w;
    const float* x = preds + (size_t)row * CC;

    float a = x[l];
    float b2 = (l + 64 < CC) ? x[l + 64] : -INFINITY;
    float mx = fmaxf(a, b2);
    for (int m = 32; m; m >>= 1) mx = fmaxf(mx, __shfl_xor(mx, m));
    float e = __expf(a - mx) + ((l + 64 < CC) ? __expf(b2 - mx) : 0.0f);
    for (int m = 32; m; m >>= 1) e += __shfl_xor(e, m);

    __shared__ float part[4];
    if (l == 0) {
        int tg = tgt[row];
        part[w] = mx + logf(e) - x[tg];
    }
    __syncthreads();
    if (threadIdx.x == 0)
        partials[blockIdx.x] = part[0] + part[1] + part[2] + part[3];
}

// ---------------- stage 4: final mean ----------------------------------------
__global__ void final_reduce_kernel(const float* __restrict__ partials, int n,
                                    float* __restrict__ out) {
    float s = 0.f;
    for (int i = threadIdx.x; i < n; i += 256) s += partials[i];
    for (int m = 32; m; m >>= 1) s += __shfl_xor(s, m);
    __shared__ float ps[4];
    if ((threadIdx.x & 63) == 0) ps[threadIdx.x >> 6] = s;
    __syncthreads();
    if (threadIdx.x == 0)
        out[0] = (ps[0] + ps[1] + ps[2] + ps[3]) / (float)(BB * PP);
}

extern "C" void kernel_launch(void* const* d_in, const int* in_sizes, int n_in,
                              void* d_out, int out_size, void* d_ws, size_t ws_size,
                              hipStream_t stream) {
    const float* pairs = (const float*)d_in[0];  // [B,P,1536]
    const float* preds = (const float*)d_in[1];  // [B,P,97]
    const float* trip  = (const float*)d_in[2];  // [B,T,1537]
    float* out = (float*)d_out;

    char* ws = (char*)d_ws;
    size_t vec_bytes = (size_t)BB * PP * DD * sizeof(__hip_bfloat16);  // 25,165,824
    __hip_bfloat16* ph = (__hip_bfloat16*)(ws);
    __hip_bfloat16* pt = (__hip_bfloat16*)(ws + vec_bytes);
    __hip_bfloat16* gh = (__hip_bfloat16*)(ws + 2 * vec_bytes);
    __hip_bfloat16* gt = (__hip_bfloat16*)(ws + 3 * vec_bytes);
    char* p = ws + 4 * vec_bytes;
    int* rel = (int*)p;              p += (size_t)BB * TT * sizeof(int);      // 64KB
    int* tgt = (int*)p;              p += (size_t)BB * PP * sizeof(int);      // 64KB
    float* cand_v = (float*)p;       p += (size_t)BB * PP * 4 * sizeof(float);// 256KB
    int* cand_t = (int*)p;           p += (size_t)BB * PP * 4 * sizeof(int);  // 256KB
    float* partials = cand_v;        // reused after merge consumed cand_v

    norm_pairs_kernel<<<BB * PP, 256, 0, stream>>>(pairs, ph, pt);
    norm_trip_kernel<<<BB * TT, 256, 0, stream>>>(trip, gh, gt, rel);
    match_kernel<<<512, 512, 131072, stream>>>(ph, pt, gh, gt, cand_v, cand_t);
    merge_kernel<<<BB * PP / 256, 256, 0, stream>>>(cand_v, cand_t, rel, tgt);
    nll_kernel<<<BB * PP / 4, 256, 0, stream>>>(preds, tgt, partials);
    final_reduce_kernel<<<1, 256, 0, stream>>>(partials, BB * PP / 4, out);
}

// Round 4
// 125.312 us; speedup vs baseline: 3.3598x; 2.1700x over previous
//
#include <hip/hip_runtime.h>
#include <hip/hip_bf16.h>
#include <math.h>

#define DD 768
#define BB 32
#define PP 512
#define TT 512
#define CC 97
#define THRESH 0.8f
#define BK 32

typedef __attribute__((ext_vector_type(8))) short short8;
typedef __attribute__((ext_vector_type(4))) float f32x4;

// ---------------- stage 1a: normalize entity pairs -> bf16 unit vecs ----------
__global__ void norm_pairs_kernel(const float* __restrict__ pairs,
                                  __hip_bfloat16* __restrict__ ph,
                                  __hip_bfloat16* __restrict__ pt) {
    int row = blockIdx.x;            // B*P rows
    int tid = threadIdx.x;           // 256 threads
    const float* src = pairs + (size_t)row * (2 * DD);

    float xh[3], xt[3];
    float sh = 0.f, st = 0.f;
#pragma unroll
    for (int j = 0; j < 3; ++j) {
        xh[j] = src[j * 256 + tid];
        xt[j] = src[DD + j * 256 + tid];
        sh += xh[j] * xh[j];
        st += xt[j] * xt[j];
    }
    for (int off = 32; off; off >>= 1) {
        sh += __shfl_down(sh, off);
        st += __shfl_down(st, off);
    }
    __shared__ float red[2][5];
    int wid = tid >> 6, lane = tid & 63;
    if (lane == 0) { red[0][wid] = sh; red[1][wid] = st; }
    __syncthreads();
    if (tid == 0) {
        float a = red[0][0] + red[0][1] + red[0][2] + red[0][3];
        float b = red[1][0] + red[1][1] + red[1][2] + red[1][3];
        red[0][4] = 1.0f / fmaxf(sqrtf(a), 1e-8f);
        red[1][4] = 1.0f / fmaxf(sqrtf(b), 1e-8f);
    }
    __syncthreads();
    float ih = red[0][4], it = red[1][4];
    __hip_bfloat16* dh = ph + (size_t)row * DD;
    __hip_bfloat16* dt = pt + (size_t)row * DD;
#pragma unroll
    for (int j = 0; j < 3; ++j) {
        dh[j * 256 + tid] = __float2bfloat16(xh[j] * ih);
        dt[j * 256 + tid] = __float2bfloat16(xt[j] * it);
    }
}

// ---------------- stage 1b: normalize triplets -> bf16 unit vecs + rel ids ----
__global__ void norm_trip_kernel(const float* __restrict__ trip,
                                 __hip_bfloat16* __restrict__ gh,
                                 __hip_bfloat16* __restrict__ gt,
                                 int* __restrict__ rel) {
    int row = blockIdx.x;            // B*T rows
    int tid = threadIdx.x;
    const float* src = trip + (size_t)row * (2 * DD + 1);

    float xh[3], xt[3];
    float sh = 0.f, st = 0.f;
#pragma unroll
    for (int j = 0; j < 3; ++j) {
        xh[j] = src[j * 256 + tid];
        xt[j] = src[DD + 1 + j * 256 + tid];
        sh += xh[j] * xh[j];
        st += xt[j] * xt[j];
    }
    for (int off = 32; off; off >>= 1) {
        sh += __shfl_down(sh, off);
        st += __shfl_down(st, off);
    }
    __shared__ float red[2][5];
    int wid = tid >> 6, lane = tid & 63;
    if (lane == 0) { red[0][wid] = sh; red[1][wid] = st; }
    __syncthreads();
    if (tid == 0) {
        float a = red[0][0] + red[0][1] + red[0][2] + red[0][3];
        float b = red[1][0] + red[1][1] + red[1][2] + red[1][3];
        red[0][4] = 1.0f / fmaxf(sqrtf(a), 1e-8f);
        red[1][4] = 1.0f / fmaxf(sqrtf(b), 1e-8f);
        rel[row] = (int)src[DD];
    }
    __syncthreads();
    float ih = red[0][4], it = red[1][4];
    __hip_bfloat16* dh = gh + (size_t)row * DD;
    __hip_bfloat16* dt = gt + (size_t)row * DD;
#pragma unroll
    for (int j = 0; j < 3; ++j) {
        dh[j * 256 + tid] = __float2bfloat16(xh[j] * ih);
        dt[j * 256 + tid] = __float2bfloat16(xt[j] * it);
    }
}

// ---------------- stage 2: reg-staged 2-phase dual-GEMM + thresholded argmax --
// Block: 512 thr = 8 waves. Tile: 128p x 64t of one batch. BK=32, single 24KB
// LDS buffer, 2 barriers/step, next step's global loads issued before MFMAs.
// Wave w: p-rows [(w&3)*32, +32), t-cols [(w>>2)*32, +32), computes BOTH H & T
// (no cross-wave exchange). LDS row pitch 64B -> ds_read_b128 at the 8-cyc
// floor, ds_write fully contiguous.
__global__ __launch_bounds__(512, 4) void match_kernel(
        const __hip_bfloat16* __restrict__ ph, const __hip_bfloat16* __restrict__ pt,
        const __hip_bfloat16* __restrict__ gh, const __hip_bfloat16* __restrict__ gt,
        float* __restrict__ cand_v, int* __restrict__ cand_t) {
    __shared__ __align__(16) char smem[24576];   // Ah 8K | At 8K | Bh 4K | Bt 4K
    __shared__ float bwv[128][2];
    __shared__ int   bwt[128][2];

    // XCD swizzle (1024 blocks, 1024%8==0 -> bijective): each batch's 32
    // blocks land on one XCD so its 4.7MB of panels stay L2-resident.
    int bid = blockIdx.x;
    int swz = (bid & 7) * 128 + (bid >> 3);
    int b = swz >> 5, sub = swz & 31;
    int pblk = sub >> 3, tblk = sub & 7;         // 4 p-blocks x 8 t-blocks

    int tid = threadIdx.x;
    int w = tid >> 6, l = tid & 63;
    int l15 = l & 15, lg = l >> 4;

    const __hip_bfloat16* baseA_h = ph + ((size_t)b * PP + pblk * 128) * DD;
    const __hip_bfloat16* baseA_t = pt + ((size_t)b * PP + pblk * 128) * DD;
    const __hip_bfloat16* baseB_h = gh + ((size_t)b * TT + tblk * 64) * DD;
    const __hip_bfloat16* baseB_t = gt + ((size_t)b * TT + tblk * 64) * DD;

    // staging map: 384 row-segs of 64B (4 x 16B lanes); 3 segs-slots per thread
    const __hip_bfloat16* sb[3];
    int so[3];
#pragma unroll
    for (int r = 0; r < 3; ++r) {
        int s = tid + 512 * r;
        int seg = s >> 2, ln = s & 3;
        const __hip_bfloat16* bp; int mo, ro;
        if (seg < 128)      { bp = baseA_h; mo = 0;     ro = seg; }
        else if (seg < 256) { bp = baseA_t; mo = 8192;  ro = seg - 128; }
        else if (seg < 320) { bp = baseB_h; mo = 16384; ro = seg - 256; }
        else                { bp = baseB_t; mo = 20480; ro = seg - 320; }
        sb[r] = bp + (size_t)ro * DD + ln * 8;
        so[r] = mo + ro * 64 + ln * 16;
    }

    short8 st0 = *(const short8*)(sb[0]);
    short8 st1 = *(const short8*)(sb[1]);
    short8 st2 = *(const short8*)(sb[2]);

    f32x4 aH[2][2], aT[2][2];
#pragma unroll
    for (int i = 0; i < 2; ++i)
#pragma unroll
        for (int j = 0; j < 2; ++j) {
            aH[i][j] = (f32x4){0.f, 0.f, 0.f, 0.f};
            aT[i][j] = (f32x4){0.f, 0.f, 0.f, 0.f};
        }

    int pb = (w & 3) * 32;
    int tb = (w >> 2) * 32;
    // fragment LDS byte offsets (row pitch 64B, lane's 16B k-slot = lg*16)
    int oAh0 = (pb + l15) * 64 + lg * 16;
    int oAh1 = (pb + 16 + l15) * 64 + lg * 16;
    int oAt0 = 8192 + (pb + l15) * 64 + lg * 16;
    int oAt1 = 8192 + (pb + 16 + l15) * 64 + lg * 16;
    int oBh0 = 16384 + (tb + l15) * 64 + lg * 16;
    int oBh1 = 16384 + (tb + 16 + l15) * 64 + lg * 16;
    int oBt0 = 20480 + (tb + l15) * 64 + lg * 16;
    int oBt1 = 20480 + (tb + 16 + l15) * 64 + lg * 16;

    for (int t = 0; t < DD / BK; ++t) {
        __syncthreads();                      // previous step's reads done
        *(short8*)(smem + so[0]) = st0;
        *(short8*)(smem + so[1]) = st1;
        *(short8*)(smem + so[2]) = st2;
        __syncthreads();                      // tile visible
        if (t < DD / BK - 1) {                // issue next tile's loads now;
            size_t ko = (size_t)(t + 1) * BK; // they fly under the MFMAs
            st0 = *(const short8*)(sb[0] + ko);
            st1 = *(const short8*)(sb[1] + ko);
            st2 = *(const short8*)(sb[2] + ko);
        }
        short8 fah0 = *(const short8*)(smem + oAh0);
        short8 fah1 = *(const short8*)(smem + oAh1);
        short8 fat0 = *(const short8*)(smem + oAt0);
        short8 fat1 = *(const short8*)(smem + oAt1);
        short8 fbh0 = *(const short8*)(smem + oBh0);
        short8 fbh1 = *(const short8*)(smem + oBh1);
        short8 fbt0 = *(const short8*)(smem + oBt0);
        short8 fbt1 = *(const short8*)(smem + oBt1);
        aH[0][0] = __builtin_amdgcn_mfma_f32_16x16x32_bf16(fah0, fbh0, aH[0][0], 0, 0, 0);
        aH[0][1] = __builtin_amdgcn_mfma_f32_16x16x32_bf16(fah0, fbh1, aH[0][1], 0, 0, 0);
        aH[1][0] = __builtin_amdgcn_mfma_f32_16x16x32_bf16(fah1, fbh0, aH[1][0], 0, 0, 0);
        aH[1][1] = __builtin_amdgcn_mfma_f32_16x16x32_bf16(fah1, fbh1, aH[1][1], 0, 0, 0);
        aT[0][0] = __builtin_amdgcn_mfma_f32_16x16x32_bf16(fat0, fbt0, aT[0][0], 0, 0, 0);
        aT[0][1] = __builtin_amdgcn_mfma_f32_16x16x32_bf16(fat0, fbt1, aT[0][1], 0, 0, 0);
        aT[1][0] = __builtin_amdgcn_mfma_f32_16x16x32_bf16(fat1, fbt0, aT[1][0], 0, 0, 0);
        aT[1][1] = __builtin_amdgcn_mfma_f32_16x16x32_bf16(fat1, fbt1, aT[1][1], 0, 0, 0);
    }

    // epilogue: threshold + score + argmax. C layout: p = i*16+lg*4+r, t = j*16+l15.
#pragma unroll
    for (int i = 0; i < 2; ++i) {
#pragma unroll
        for (int r = 0; r < 4; ++r) {
            float bv = -INFINITY; int bt = 0x7fffffff;
#pragma unroll
            for (int j = 0; j < 2; ++j) {
                float h = aH[i][j][r], tl = aT[i][j][r];
                bool ok = (h > THRESH) && (tl > THRESH);
                float sc = ok ? 0.5f * (h + tl) : -INFINITY;
                int tg = tb + j * 16 + l15;
                if (sc > bv || (sc == bv && tg < bt)) { bv = sc; bt = tg; }
            }
#pragma unroll
            for (int m = 1; m < 16; m <<= 1) {
                float v2 = __shfl_xor(bv, m);
                int t2 = __shfl_xor(bt, m);
                if (v2 > bv || (v2 == bv && t2 < bt)) { bv = v2; bt = t2; }
            }
            if (l15 == 0) {
                int p = pb + i * 16 + lg * 4 + r;
                bwv[p][w >> 2] = bv;
                bwt[p][w >> 2] = bt;
            }
        }
    }
    __syncthreads();
    if (tid < 128) {
        float v = bwv[tid][0]; int t1 = bwt[tid][0];
        float v2 = bwv[tid][1]; int t2 = bwt[tid][1];
        if (v2 > v || (v2 == v && t2 < t1)) { v = v2; t1 = t2; }
        int grow = b * PP + pblk * 128 + tid;
        cand_v[(size_t)grow * 8 + tblk] = v;
        cand_t[(size_t)grow * 8 + tblk] = (v > -INFINITY) ? (tblk * 64 + t1) : 0x7fffffff;
    }
}

// ---------------- stage 2b: merge 8 t-blocks -> target class -----------------
__global__ void merge_kernel(const float* __restrict__ cand_v,
                             const int* __restrict__ cand_t,
                             const int* __restrict__ rel,
                             int* __restrict__ tgt) {
    int row = blockIdx.x * 256 + threadIdx.x;    // B*P rows
    float v = -INFINITY; int t = 0x7fffffff;
#pragma unroll
    for (int k = 0; k < 8; ++k) {
        float v2 = cand_v[(size_t)row * 8 + k];
        int t2 = cand_t[(size_t)row * 8 + k];
        if (v2 > v || (v2 == v && t2 < t)) { v = v2; t = t2; }
    }
    int b = row >> 9;
    tgt[row] = (v > -INFINITY) ? rel[b * TT + t] : 0;
}

// ---------------- stage 3: per-row NLL from log-softmax ----------------------
__global__ void nll_kernel(const float* __restrict__ preds,
                           const int* __restrict__ tgt,
                           float* __restrict__ partials) {
    int w = threadIdx.x >> 6, l = threadIdx.x & 63;
    int row = blockIdx.x * 4 + w;
    const float* x = preds + (size_t)row * CC;

    float a = x[l];
    float b2 = (l + 64 < CC) ? x[l + 64] : -INFINITY;
    float mx = fmaxf(a, b2);
    for (int m = 32; m; m >>= 1) mx = fmaxf(mx, __shfl_xor(mx, m));
    float e = __expf(a - mx) + ((l + 64 < CC) ? __expf(b2 - mx) : 0.0f);
    for (int m = 32; m; m >>= 1) e += __shfl_xor(e, m);

    __shared__ float part[4];
    if (l == 0) {
        int tg = tgt[row];
        part[w] = mx + logf(e) - x[tg];
    }
    __syncthreads();
    if (threadIdx.x == 0)
        partials[blockIdx.x] = part[0] + part[1] + part[2] + part[3];
}

// ---------------- stage 4: final mean ----------------------------------------
__global__ void final_reduce_kernel(const float* __restrict__ partials, int n,
                                    float* __restrict__ out) {
    float s = 0.f;
    for (int i = threadIdx.x; i < n; i += 256) s += partials[i];
    for (int m = 32; m; m >>= 1) s += __shfl_xor(s, m);
    __shared__ float ps[4];
    if ((threadIdx.x & 63) == 0) ps[threadIdx.x >> 6] = s;
    __syncthreads();
    if (threadIdx.x == 0)
        out[0] = (ps[0] + ps[1] + ps[2] + ps[3]) / (float)(BB * PP);
}

extern "C" void kernel_launch(void* const* d_in, const int* in_sizes, int n_in,
                              void* d_out, int out_size, void* d_ws, size_t ws_size,
                              hipStream_t stream) {
    const float* pairs = (const float*)d_in[0];  // [B,P,1536]
    const float* preds = (const float*)d_in[1];  // [B,P,97]
    const float* trip  = (const float*)d_in[2];  // [B,T,1537]
    float* out = (float*)d_out;

    char* ws = (char*)d_ws;
    size_t vec_bytes = (size_t)BB * PP * DD * sizeof(__hip_bfloat16);  // 25,165,824
    __hip_bfloat16* ph = (__hip_bfloat16*)(ws);
    __hip_bfloat16* pt = (__hip_bfloat16*)(ws + vec_bytes);
    __hip_bfloat16* gh = (__hip_bfloat16*)(ws + 2 * vec_bytes);
    __hip_bfloat16* gt = (__hip_bfloat16*)(ws + 3 * vec_bytes);
    char* p = ws + 4 * vec_bytes;
    int* rel = (int*)p;              p += (size_t)BB * TT * sizeof(int);        // 64KB
    int* tgt = (int*)p;              p += (size_t)BB * PP * sizeof(int);        // 64KB
    float* cand_v = (float*)p;       p += (size_t)BB * PP * 8 * sizeof(float);  // 512KB
    int* cand_t = (int*)p;           p += (size_t)BB * PP * 8 * sizeof(int);    // 512KB
    float* partials = (float*)p;                                                // 16KB

    norm_pairs_kernel<<<BB * PP, 256, 0, stream>>>(pairs, ph, pt);
    norm_trip_kernel<<<BB * TT, 256, 0, stream>>>(trip, gh, gt, rel);
    match_kernel<<<BB * 4 * 8, 512, 0, stream>>>(ph, pt, gh, gt, cand_v, cand_t);
    merge_kernel<<<BB * PP / 256, 256, 0, stream>>>(cand_v, cand_t, rel, tgt);
    nll_kernel<<<BB * PP / 4, 256, 0, stream>>>(preds, tgt, partials);
    final_reduce_kernel<<<1, 256, 0, stream>>>(partials, BB * PP / 4, out);
}